// Round 4
// baseline (190.546 us; speedup 1.0000x reference)
//
#include <hip/hip_runtime.h>
#include <hip/hip_bf16.h>
#include <math.h>
#include <limits.h>

// Problem dims
constexpr int NB    = 4096;   // batch
constexpr int ROWS2 = NB * 12;            // 49152 rows for the 2->100->100->2 MLPs
constexpr int MLP2_BLOCKS = ROWS2 / 64;   // 768 (64 rows/block, 4 lanes/row)

// workspace layout (float offsets)
constexpr size_t WS_Y1    = 0;              // NB*24
constexpr size_t WS_YHAT  = 98304;          // NB*24
constexpr size_t WS_YHAT1 = 196608;         // NB*24
constexpr size_t WS_YM    = 294912;         // 24
constexpr size_t WS_U2T   = 294936;         // 24*256 (transposed: [c][m])
constexpr size_t WS_EB    = 301080;         // 24*58 precomputed prior params
constexpr size_t WS_KMM   = 302472;         // 48 ints (kmin[24], kmax[24])
constexpr size_t WS_PART  = 302520;         // 768*24 per-block mean partials
constexpr size_t WS_TBL   = 320952;         // 24*64*256 table of log(pdf+1e-9)
constexpr size_t WS_END   = WS_TBL + 24 * 64 * 256;   // 714168 floats (~2.86 MB)

constexpr float STEP_ODD = 0.8660254037844386f;   // sqrt(3)/2
constexpr float INV_ODD  = 1.1547005383792517f;   // 2/sqrt(3)

__device__ __forceinline__ float lrelu(float x) { return x >= 0.f ? x : 0.01f * x; }
__device__ __forceinline__ float rcp_fast(float x) { return __builtin_amdgcn_rcpf(x); }

__device__ __forceinline__ float tanh_fast(float x) {
    float xx = fminf(fmaxf(x, -15.f), 15.f);
    float e = __expf(xx + xx);
    return fmaf(-2.f, rcp_fast(e + 1.f), 1.f);
}
__device__ __forceinline__ float splus(float x) {
    return fmaxf(x, 0.f) + __logf(1.f + __expf(-fabsf(x)));
}
__device__ __forceinline__ float splus_precise(float x) {
    return fmaxf(x, 0.f) + log1pf(expf(-fabsf(x)));
}

// exact A2 hex lattice nearest-point quantizer; matches jnp.round (rint = RNE)
__device__ __forceinline__ void hexq(float p0, float p1, float& q0, float& q1) {
    const float S3 = 1.7320508075688772f;
    const float H3 = 0.8660254037844386f;
    float c00 = rintf(p0);
    float c01 = rintf(p1 / S3) * S3;
    float c10 = rintf(p0 - 0.5f) + 0.5f;
    float c11 = rintf((p1 - H3) / S3) * S3 + H3;
    float d0 = (p0 - c00) * (p0 - c00) + (p1 - c01) * (p1 - c01);
    float d1 = (p0 - c10) * (p0 - c10) + (p1 - c11) * (p1 - c11);
    bool take0 = d0 <= d1;
    q0 = take0 ? c00 : c10;
    q1 = take0 ? c01 : c11;
}

// per-channel prior chain: log(pdf + 1e-9) at point p, params P (58 floats)
__device__ __forceinline__ float logpdf_ch(const float* __restrict__ P, float p) {
    float w00 = P[0], w01 = P[1], w02 = P[2];
    float z0 = fmaf(w00, p, P[3]);
    float z1 = fmaf(w01, p, P[4]);
    float z2 = fmaf(w02, p, P[5]);
    float a0 = P[6], a1 = P[7], a2 = P[8];
    float e0 = tanh_fast(z0), e1 = tanh_fast(z1), e2 = tanh_fast(z2);
    float h0 = fmaf(a0, e0, z0), h1 = fmaf(a1, e1, z1), h2 = fmaf(a2, e2, z2);
    float t0 = w00 * fmaf(a0, fmaf(-e0, e0, 1.f), 1.f);
    float t1 = w01 * fmaf(a1, fmaf(-e1, e1, 1.f), 1.f);
    float t2 = w02 * fmaf(a2, fmaf(-e2, e2, 1.f), 1.f);

#define EB_LAYER(O)                                                            \
    {                                                                          \
        float z0n = fmaf(P[O+0], h0, fmaf(P[O+1], h1, fmaf(P[O+2], h2, P[O+9])));  \
        float z1n = fmaf(P[O+3], h0, fmaf(P[O+4], h1, fmaf(P[O+5], h2, P[O+10]))); \
        float z2n = fmaf(P[O+6], h0, fmaf(P[O+7], h1, fmaf(P[O+8], h2, P[O+11]))); \
        float s0 = fmaf(P[O+0], t0, fmaf(P[O+1], t1, P[O+2] * t2));            \
        float s1 = fmaf(P[O+3], t0, fmaf(P[O+4], t1, P[O+5] * t2));            \
        float s2 = fmaf(P[O+6], t0, fmaf(P[O+7], t1, P[O+8] * t2));            \
        float g0 = P[O+12], g1 = P[O+13], g2 = P[O+14];                        \
        float q0 = tanh_fast(z0n), q1 = tanh_fast(z1n), q2 = tanh_fast(z2n);   \
        h0 = fmaf(g0, q0, z0n); h1 = fmaf(g1, q1, z1n); h2 = fmaf(g2, q2, z2n); \
        t0 = s0 * fmaf(g0, fmaf(-q0, q0, 1.f), 1.f);                           \
        t1 = s1 * fmaf(g1, fmaf(-q1, q1, 1.f), 1.f);                           \
        t2 = s2 * fmaf(g2, fmaf(-q2, q2, 1.f), 1.f);                           \
    }
    EB_LAYER(9)
    EB_LAYER(24)
    EB_LAYER(39)
#undef EB_LAYER

    float L = fmaf(P[54], h0, fmaf(P[55], h1, fmaf(P[56], h2, P[57])));
    float T = fmaf(P[54], t0, fmaf(P[55], t1, P[56] * t2));
    float Lc = fminf(fmaxf(L, -30.f), 30.f);
    float sg = rcp_fast(1.f + __expf(-Lc));
    float pdf = sg * (1.f - sg) * T;
    return __logf(pdf + 1e-9f);
}

// ---------------------------------------------------------------------------
// K0: precompute prior params, u2^T, and init kmm
// ---------------------------------------------------------------------------
__global__ __launch_bounds__(256) void k_prep(
    const float* __restrict__ H0p, const float* __restrict__ H1p,
    const float* __restrict__ H2p, const float* __restrict__ H3p,
    const float* __restrict__ H4p,
    const float* __restrict__ b0p, const float* __restrict__ b1p,
    const float* __restrict__ b2p, const float* __restrict__ b3p,
    const float* __restrict__ b4p,
    const float* __restrict__ a0p, const float* __restrict__ a1p,
    const float* __restrict__ a2p, const float* __restrict__ a3p,
    const float* __restrict__ u, float* __restrict__ eb, float* __restrict__ u2t,
    int* __restrict__ kmm)
{
    int tid = threadIdx.x;
    if (tid < 24) {
        int c = tid;
        float* P = eb + c * 58;
        for (int j = 0; j < 3; ++j) P[j]      = splus_precise(H0p[c*3+j]);
        for (int j = 0; j < 3; ++j) P[3+j]    = b0p[c*3+j];
        for (int j = 0; j < 3; ++j) P[6+j]    = tanhf(a0p[c*3+j]);
        for (int j = 0; j < 9; ++j) P[9+j]    = splus_precise(H1p[c*9+j]);
        for (int j = 0; j < 3; ++j) P[18+j]   = b1p[c*3+j];
        for (int j = 0; j < 3; ++j) P[21+j]   = tanhf(a1p[c*3+j]);
        for (int j = 0; j < 9; ++j) P[24+j]   = splus_precise(H2p[c*9+j]);
        for (int j = 0; j < 3; ++j) P[33+j]   = b2p[c*3+j];
        for (int j = 0; j < 3; ++j) P[36+j]   = tanhf(a2p[c*3+j]);
        for (int j = 0; j < 9; ++j) P[39+j]   = splus_precise(H3p[c*9+j]);
        for (int j = 0; j < 3; ++j) P[48+j]   = b3p[c*3+j];
        for (int j = 0; j < 3; ++j) P[51+j]   = tanhf(a3p[c*3+j]);
        for (int j = 0; j < 3; ++j) P[54+j]   = splus_precise(H4p[c*3+j]);
        P[57] = b4p[c];
        kmm[tid]      = INT_MAX;
        kmm[24 + tid] = INT_MIN;
    }
    int m = tid;
    if (m < 256) {
        for (int j = 0; j < 12; ++j) {
            float a  = u[m*24 + 2*j];
            float bb = u[m*24 + 2*j + 1];
            float p0 = fmaf(0.5f, bb, a);
            float p1 = 0.8660254037844386f * bb;
            float q0, q1; hexq(p0, p1, q0, q1);
            u2t[(2*j)   * 256 + m] = p0 - q0;
            u2t[(2*j+1) * 256 + m] = p1 - q1;
        }
    }
}

// ---------------------------------------------------------------------------
// K1/K4: per-row MLP 2 -> 100 (lrelu) -> 100 (lrelu) -> 2 over 49152 rows.
// j-split-4: 4 lanes/row, each lane owns h[25] (one j-quartile). Layer-1 dot
// products complete via shfl_xor butterfly (bit-deterministic, commutative).
// w1 staged as [i][q][28] zero-padded quarters: 16B-aligned float4, 4-addr
// broadcast, conflict-free. h[25] in VGPRs -> no spill, 12 waves/CU.
// MEAN=1: also emit per-block channel partial sums for the EMA mean.
// ---------------------------------------------------------------------------
template <int MEAN>
__global__ __launch_bounds__(256, 1) void k_mlp2(
    const float* __restrict__ in,
    const float* __restrict__ w0, const float* __restrict__ b0,
    const float* __restrict__ w1, const float* __restrict__ b1,
    const float* __restrict__ w2, const float* __restrict__ b2,
    float* __restrict__ out, float* __restrict__ partial)
{
    __shared__ alignas(16) float sw1[100 * 112];   // [i][q][28], pad zeroed
    __shared__ float sw0[200], sb0[100], sb1[100], sw2[200], sb2[2];
    __shared__ float S[64][2];
    int tid = threadIdx.x;
    for (int t = tid; t < 11200; t += 256) {
        int rowi = t / 112, rem = t - rowi * 112;
        int qq = rem / 28, jx = rem - qq * 28;
        sw1[t] = (jx < 25) ? w1[rowi * 100 + qq * 25 + jx] : 0.f;
    }
    for (int i = tid; i < 200; i += 256) { sw0[i] = w0[i]; sw2[i] = w2[i]; }
    for (int i = tid; i < 100; i += 256) { sb0[i] = b0[i]; sb1[i] = b1[i]; }
    if (tid < 2) sb2[tid] = b2[tid];
    __syncthreads();

    int q = tid & 3, r = tid >> 2;
    int row = blockIdx.x * 64 + r;
    float2 xv = ((const float2*)in)[row];

    float h[28];
#pragma unroll
    for (int jx = 0; jx < 25; ++jx) {
        int j = q * 25 + jx;
        h[jx] = lrelu(fmaf(sw0[2*j], xv.x, fmaf(sw0[2*j+1], xv.y, sb0[j])));
    }
    h[25] = h[26] = h[27] = 0.f;

    float y0 = sb2[0], y1 = sb2[1];
#pragma unroll 2
    for (int i = 0; i < 100; ++i) {
        const float4* wr = (const float4*)&sw1[i * 112 + q * 28];
        float s0 = 0.f, s1 = 0.f;
#pragma unroll
        for (int jj = 0; jj < 7; ++jj) {
            float4 w = wr[jj];
            if (jj & 1) {
                s1 = fmaf(w.x, h[4*jj], s1);   s1 = fmaf(w.y, h[4*jj+1], s1);
                s1 = fmaf(w.z, h[4*jj+2], s1); s1 = fmaf(w.w, h[4*jj+3], s1);
            } else {
                s0 = fmaf(w.x, h[4*jj], s0);   s0 = fmaf(w.y, h[4*jj+1], s0);
                s0 = fmaf(w.z, h[4*jj+2], s0); s0 = fmaf(w.w, h[4*jj+3], s0);
            }
        }
        float s = s0 + s1;
        s += __shfl_xor(s, 1);
        s += __shfl_xor(s, 2);
        float a = lrelu(s + sb1[i]);          // bias added once, after reduce
        y0 = fmaf(sw2[i], a, y0);
        y1 = fmaf(sw2[100 + i], a, y1);
    }
    if (q == 0) {
        float2 yv; yv.x = y0; yv.y = y1;
        ((float2*)out)[row] = yv;
    }

    if (MEAN) {
        if (q == 0) { S[r][0] = y0; S[r][1] = y1; }
        __syncthreads();
        if (tid < 24) {
            int j = tid >> 1, par = tid & 1;
            int base = (blockIdx.x * 64) % 12;
            int k0 = (j - base + 12) % 12;
            float s = 0.f;
            for (int k = k0; k < 64; k += 12) s += S[k][par];
            partial[blockIdx.x * 24 + tid] = s;
        }
    }
}

// ---------------------------------------------------------------------------
// K2: finish the EMA mean from 768 per-block partials (1 block, sub-us)
// ---------------------------------------------------------------------------
__global__ __launch_bounds__(256) void k_mean_final(
    const float* __restrict__ partial, const float* __restrict__ y_mean,
    float* __restrict__ ym)
{
    int tid = threadIdx.x;
    int c = tid >> 3, s = tid & 7;
    float v = 0.f;
    if (c < 24)
        for (int g = s; g < MLP2_BLOCKS; g += 8) v += partial[g * 24 + c];
    v += __shfl_xor(v, 1); v += __shfl_xor(v, 2); v += __shfl_xor(v, 4);
    if (c < 24 && s == 0)
        ym[c] = fmaf(0.05f, y_mean[c], 0.95f * (v * (1.0f / NB)));
}

// ---------------------------------------------------------------------------
// K3: softplus MLP 24 -> 100 -> 100 -> 24 (no biases).
// 16 lanes/row (qi = i-quarter, qj = j-quarter). Each lane owns h[25] for its
// qj; layer-1 butterfly over qj (xor 1,2); layer-2 produces a 6-channel
// c-slice per lane, reduced over qi (xor 4,8). 16 rows/block, 256 blocks.
// MODE 0: input = y1 - ym, output = hexq(...) -> yhat, + kmm atomics
// MODE 1: input = yhat,    output = mlp + ym  -> yhat1
// ---------------------------------------------------------------------------
template <int MODE>
__global__ __launch_bounds__(256, 1) void k_mlp24(
    const float* __restrict__ in,
    const float* __restrict__ w0, const float* __restrict__ w1,
    const float* __restrict__ w2,
    const float* __restrict__ ymg, float* __restrict__ out,
    int* __restrict__ kmm)
{
    __shared__ alignas(16) float sw1[100 * 112];   // [i][qj][28], pad zeroed
    __shared__ alignas(16) float sw0[2400];
    __shared__ alignas(16) float sw2[2400];
    __shared__ float symL[24];
    __shared__ int kminL[24], kmaxL[24];

    int tid = threadIdx.x;
    for (int t = tid; t < 11200; t += 256) {
        int rowi = t / 112, rem = t - rowi * 112;
        int qq = rem / 28, jx = rem - qq * 28;
        sw1[t] = (jx < 25) ? w1[rowi * 100 + qq * 25 + jx] : 0.f;
    }
    for (int i = tid; i < 2400; i += 256) { sw0[i] = w0[i]; sw2[i] = w2[i]; }
    if (tid < 24) {
        symL[tid] = ymg[tid];
        kminL[tid] = INT_MAX; kmaxL[tid] = INT_MIN;
    }
    __syncthreads();

    int lane = tid & 63;
    int rsub = lane >> 4;          // row within wave (0..3)
    int qi = (lane >> 2) & 3;      // i-quarter
    int qj = lane & 3;             // j-quarter
    int wv = tid >> 6;
    int row = blockIdx.x * 16 + wv * 4 + rsub;

    float xr[24];
    const float4* xp = (const float4*)(in + row * 24);
#pragma unroll
    for (int k = 0; k < 6; ++k) {
        float4 t = xp[k];
        xr[4*k] = t.x; xr[4*k+1] = t.y; xr[4*k+2] = t.z; xr[4*k+3] = t.w;
    }
    if (MODE == 0) {
#pragma unroll
        for (int j = 0; j < 24; ++j) xr[j] -= symL[j];
    }

    // layer 0: h[jx] for j in qj's quarter
    float h[28];
#pragma unroll
    for (int jx = 0; jx < 25; ++jx) {
        int j = qj * 25 + jx;
        const float4* wr = (const float4*)&sw0[j * 24];
        float a0 = 0.f, a1 = 0.f;
#pragma unroll
        for (int kk = 0; kk < 6; ++kk) {
            float4 w = wr[kk];
            if (kk & 1) {
                a1 = fmaf(w.x, xr[4*kk], a1);   a1 = fmaf(w.y, xr[4*kk+1], a1);
                a1 = fmaf(w.z, xr[4*kk+2], a1); a1 = fmaf(w.w, xr[4*kk+3], a1);
            } else {
                a0 = fmaf(w.x, xr[4*kk], a0);   a0 = fmaf(w.y, xr[4*kk+1], a0);
                a0 = fmaf(w.z, xr[4*kk+2], a0); a0 = fmaf(w.w, xr[4*kk+3], a0);
            }
        }
        h[jx] = splus(a0 + a1);
    }
    h[25] = h[26] = h[27] = 0.f;

    // layer 1 (butterfly over qj) + layer-2 partial (6-channel c-slice)
    float y[6];
#pragma unroll
    for (int cc = 0; cc < 6; ++cc) y[cc] = 0.f;
    for (int ii = 0; ii < 25; ++ii) {
        int i = qi * 25 + ii;
        const float4* wr = (const float4*)&sw1[i * 112 + qj * 28];
        float s0 = 0.f, s1 = 0.f;
#pragma unroll
        for (int jj = 0; jj < 7; ++jj) {
            float4 w = wr[jj];
            if (jj & 1) {
                s1 = fmaf(w.x, h[4*jj], s1);   s1 = fmaf(w.y, h[4*jj+1], s1);
                s1 = fmaf(w.z, h[4*jj+2], s1); s1 = fmaf(w.w, h[4*jj+3], s1);
            } else {
                s0 = fmaf(w.x, h[4*jj], s0);   s0 = fmaf(w.y, h[4*jj+1], s0);
                s0 = fmaf(w.z, h[4*jj+2], s0); s0 = fmaf(w.w, h[4*jj+3], s0);
            }
        }
        float s = s0 + s1;
        s += __shfl_xor(s, 1);
        s += __shfl_xor(s, 2);
        float a = splus(s);
#pragma unroll
        for (int cc = 0; cc < 6; ++cc)
            y[cc] = fmaf(sw2[(qj * 6 + cc) * 100 + i], a, y[cc]);
    }
#pragma unroll
    for (int cc = 0; cc < 6; ++cc) {
        y[cc] += __shfl_xor(y[cc], 4);
        y[cc] += __shfl_xor(y[cc], 8);
    }

    if (MODE == 0) {
        if (qi == 0) {
            int c0 = qj * 6;
#pragma unroll
            for (int pr = 0; pr < 3; ++pr) {
                float q0, q1; hexq(y[2*pr], y[2*pr+1], q0, q1);
                out[row * 24 + c0 + 2*pr]     = q0;
                out[row * 24 + c0 + 2*pr + 1] = q1;
                int k0 = (int)rintf(q0 * 2.0f);
                int k1 = (int)rintf(q1 * INV_ODD);
                atomicMin(&kminL[c0 + 2*pr], k0);     atomicMax(&kmaxL[c0 + 2*pr], k0);
                atomicMin(&kminL[c0 + 2*pr + 1], k1); atomicMax(&kmaxL[c0 + 2*pr + 1], k1);
            }
        }
        __syncthreads();
        if (tid < 24) {
            atomicMin(&kmm[tid], kminL[tid]);
            atomicMax(&kmm[24 + tid], kmaxL[tid]);
        }
    } else {
        if (qi == 0) {
            int c0 = qj * 6;
#pragma unroll
            for (int cc = 0; cc < 6; ++cc)
                out[row * 24 + c0 + cc] = y[cc] + symL[c0 + cc];
        }
    }
}

// ---------------------------------------------------------------------------
// K5b: build T[c][v][m] = logpdf_c((kmin_c+v)*step_c + u2[c,m]); grid 24*64
// ---------------------------------------------------------------------------
__global__ __launch_bounds__(256) void k_table(
    const float* __restrict__ eb, const float* __restrict__ u2t,
    const int* __restrict__ kmm, float* __restrict__ tbl)
{
    int cv = blockIdx.x;
    int c = cv >> 6, v = cv & 63;
    int m = threadIdx.x;
    float step = (c & 1) ? STEP_ODD : 0.5f;
    float val = (float)(kmm[c] + v) * step;
    float p = val + u2t[c * 256 + m];
    tbl[cv * 256 + m] = logpdf_ch(eb + c * 58, p);
}

// ---------------------------------------------------------------------------
// K5c: MC likelihood via table gather; shuffle-based logsumexp.
// ---------------------------------------------------------------------------
__global__ __launch_bounds__(256) void k_mc_tbl(
    const float* __restrict__ yhat, const float* __restrict__ u2t,
    const float* __restrict__ eb, const int* __restrict__ kmm,
    const float* __restrict__ tbl, float* __restrict__ lik)
{
    __shared__ float redm[4], reds[4];
    int tid = threadIdx.x;
    int wv = tid >> 6;
    int b = blockIdx.x;

    float y[24];
    const float4* yr = (const float4*)(yhat + b * 24);
#pragma unroll
    for (int k4 = 0; k4 < 6; ++k4) {
        float4 t = yr[k4];
        y[4*k4] = t.x; y[4*k4+1] = t.y; y[4*k4+2] = t.z; y[4*k4+3] = t.w;
    }

    float lp = 0.f;
    unsigned miss = 0;
#pragma unroll
    for (int c = 0; c < 24; ++c) {
        float inv = (c & 1) ? INV_ODD : 2.0f;
        int k = (int)rintf(y[c] * inv);
        int idx = k - kmm[c];
        if (idx >= 0 && idx < 64)
            lp += tbl[(c * 64 + idx) * 256 + tid];
        else
            miss |= (1u << c);
    }
    while (miss) {   // rare fallback: channel exceeded 64 lattice slots
        int c = __ffs(miss) - 1;
        miss &= miss - 1;
        lp += logpdf_ch(eb + c * 58, y[c] + u2t[c * 256 + tid]);
    }

    float m = lp;
#pragma unroll
    for (int off = 1; off < 64; off <<= 1) m = fmaxf(m, __shfl_xor(m, off));
    if ((tid & 63) == 0) redm[wv] = m;
    __syncthreads();
    float mx = fmaxf(fmaxf(redm[0], redm[1]), fmaxf(redm[2], redm[3]));
    float e = __expf(lp - mx);
#pragma unroll
    for (int off = 1; off < 64; off <<= 1) e += __shfl_xor(e, off);
    if ((tid & 63) == 0) reds[wv] = e;
    __syncthreads();
    if (tid == 0)
        lik[b] = mx + __logf(reds[0] + reds[1] + reds[2] + reds[3])
               - 7.271269879190247f;  // -log(NMC) + LOG_VOL
}

// ---------------------------------------------------------------------------
// K5 fallback (ws too small): direct MC
// ---------------------------------------------------------------------------
__global__ __launch_bounds__(256) void k_mc_direct(
    const float* __restrict__ yhat, const float* __restrict__ u2t,
    const float* __restrict__ eb, float* __restrict__ lik)
{
    __shared__ alignas(16) float sU[24 * 256];
    __shared__ float redm[4], reds[4];
    int tid = threadIdx.x;
    int wv = tid >> 6;
    int b = blockIdx.x;
    for (int i = tid; i < 1536; i += 256)
        ((float4*)sU)[i] = ((const float4*)u2t)[i];
    __syncthreads();

    float lp = 0.f;
    for (int c = 0; c < 24; ++c)
        lp += logpdf_ch(eb + c * 58, yhat[b * 24 + c] + sU[c * 256 + tid]);

    float m = lp;
#pragma unroll
    for (int off = 1; off < 64; off <<= 1) m = fmaxf(m, __shfl_xor(m, off));
    if ((tid & 63) == 0) redm[wv] = m;
    __syncthreads();
    float mx = fmaxf(fmaxf(redm[0], redm[1]), fmaxf(redm[2], redm[3]));
    float e = __expf(lp - mx);
#pragma unroll
    for (int off = 1; off < 64; off <<= 1) e += __shfl_xor(e, off);
    if ((tid & 63) == 0) reds[wv] = e;
    __syncthreads();
    if (tid == 0)
        lik[b] = mx + __logf(reds[0] + reds[1] + reds[2] + reds[3])
               - 7.271269879190247f;
}

// ---------------------------------------------------------------------------
extern "C" void kernel_launch(void* const* d_in, const int* in_sizes, int n_in,
                              void* d_out, int out_size, void* d_ws, size_t ws_size,
                              hipStream_t stream)
{
    (void)in_sizes; (void)n_in; (void)out_size;
    const float* x      = (const float*)d_in[0];
    const float* y_mean = (const float*)d_in[1];
    const float* u      = (const float*)d_in[2];
    const float* ga_w0  = (const float*)d_in[3];
    const float* ga_b0  = (const float*)d_in[4];
    const float* ga_w1  = (const float*)d_in[5];
    const float* ga_b1  = (const float*)d_in[6];
    const float* ga_w2  = (const float*)d_in[7];
    const float* ga_b2  = (const float*)d_in[8];
    const float* gs_w0  = (const float*)d_in[9];
    const float* gs_b0  = (const float*)d_in[10];
    const float* gs_w1  = (const float*)d_in[11];
    const float* gs_b1  = (const float*)d_in[12];
    const float* gs_w2  = (const float*)d_in[13];
    const float* gs_b2  = (const float*)d_in[14];
    const float* gac_w0 = (const float*)d_in[15];
    const float* gac_w1 = (const float*)d_in[16];
    const float* gac_w2 = (const float*)d_in[17];
    const float* gsc_w0 = (const float*)d_in[18];
    const float* gsc_w1 = (const float*)d_in[19];
    const float* gsc_w2 = (const float*)d_in[20];
    const float* eb_H0  = (const float*)d_in[21];
    const float* eb_H1  = (const float*)d_in[22];
    const float* eb_H2  = (const float*)d_in[23];
    const float* eb_H3  = (const float*)d_in[24];
    const float* eb_H4  = (const float*)d_in[25];
    const float* eb_b0  = (const float*)d_in[26];
    const float* eb_b1  = (const float*)d_in[27];
    const float* eb_b2  = (const float*)d_in[28];
    const float* eb_b3  = (const float*)d_in[29];
    const float* eb_b4  = (const float*)d_in[30];
    const float* eb_a0  = (const float*)d_in[31];
    const float* eb_a1  = (const float*)d_in[32];
    const float* eb_a2  = (const float*)d_in[33];
    const float* eb_a3  = (const float*)d_in[34];

    float* ws    = (float*)d_ws;
    float* y1    = ws + WS_Y1;
    float* yhat  = ws + WS_YHAT;
    float* yhat1 = ws + WS_YHAT1;
    float* ym    = ws + WS_YM;
    float* u2t   = ws + WS_U2T;
    float* eb    = ws + WS_EB;
    int*   kmm   = (int*)(ws + WS_KMM);
    float* part  = ws + WS_PART;
    float* tbl   = ws + WS_TBL;
    float* xhat  = (float*)d_out;
    float* lik   = (float*)d_out + 98304;

    bool use_tbl = ws_size >= WS_END * sizeof(float);

    k_prep<<<1, 256, 0, stream>>>(eb_H0, eb_H1, eb_H2, eb_H3, eb_H4,
                                  eb_b0, eb_b1, eb_b2, eb_b3, eb_b4,
                                  eb_a0, eb_a1, eb_a2, eb_a3, u, eb, u2t, kmm);
    k_mlp2<1><<<MLP2_BLOCKS, 256, 0, stream>>>(x, ga_w0, ga_b0, ga_w1, ga_b1,
                                               ga_w2, ga_b2, y1, part);
    k_mean_final<<<1, 256, 0, stream>>>(part, y_mean, ym);
    k_mlp24<0><<<NB / 16, 256, 0, stream>>>(y1, gac_w0, gac_w1, gac_w2, ym,
                                            yhat, kmm);
    if (use_tbl)
        k_table<<<24 * 64, 256, 0, stream>>>(eb, u2t, kmm, tbl);
    k_mlp24<1><<<NB / 16, 256, 0, stream>>>(yhat, gsc_w0, gsc_w1, gsc_w2, ym,
                                            yhat1, kmm);
    k_mlp2<0><<<MLP2_BLOCKS, 256, 0, stream>>>(yhat1, gs_w0, gs_b0, gs_w1, gs_b1,
                                               gs_w2, gs_b2, xhat, nullptr);
    if (use_tbl)
        k_mc_tbl<<<NB, 256, 0, stream>>>(yhat, u2t, eb, kmm, tbl, lik);
    else
        k_mc_direct<<<NB, 256, 0, stream>>>(yhat, u2t, eb, lik);
}

// Round 5
// 178.139 us; speedup vs baseline: 1.0696x; 1.0696x over previous
//
#include <hip/hip_runtime.h>
#include <hip/hip_bf16.h>
#include <math.h>
#include <limits.h>

// Problem dims
constexpr int NB    = 4096;   // batch
constexpr int ROWS2 = NB * 12;            // 49152 rows for the 2->100->100->2 MLPs
constexpr int G2_BLOCKS = ROWS2 / 64;     // 768 (64 rows/block)

// workspace layout (float offsets)
constexpr size_t WS_Y1    = 0;              // NB*24
constexpr size_t WS_YHAT  = 98304;          // NB*24
constexpr size_t WS_YHAT1 = 196608;         // NB*24
constexpr size_t WS_YM    = 294912;         // 24
constexpr size_t WS_U2T   = 294936;         // 24*256 (transposed: [c][m])
constexpr size_t WS_EB    = 301080;         // 24*58 precomputed prior params
constexpr size_t WS_KMM   = 302472;         // 48 ints (kmin[24], kmax[24])
constexpr size_t WS_PART  = 302520;         // 768*24 per-block mean partials
constexpr size_t WS_TBL   = 320952;         // 24*64*256 table of log(pdf+1e-9)
constexpr size_t WS_END   = WS_TBL + 24 * 64 * 256;   // 714168 floats (~2.86 MB)

constexpr float STEP_ODD = 0.8660254037844386f;   // sqrt(3)/2
constexpr float INV_ODD  = 1.1547005383792517f;   // 2/sqrt(3)

__device__ __forceinline__ float lrelu(float x) { return x >= 0.f ? x : 0.01f * x; }
__device__ __forceinline__ float rcp_fast(float x) { return __builtin_amdgcn_rcpf(x); }

__device__ __forceinline__ float tanh_fast(float x) {
    float xx = fminf(fmaxf(x, -15.f), 15.f);
    float e = __expf(xx + xx);
    return fmaf(-2.f, rcp_fast(e + 1.f), 1.f);
}
__device__ __forceinline__ float splus(float x) {
    return fmaxf(x, 0.f) + __logf(1.f + __expf(-fabsf(x)));
}
__device__ __forceinline__ float splus_precise(float x) {
    return fmaxf(x, 0.f) + log1pf(expf(-fabsf(x)));
}

__device__ __forceinline__ void fma4(float4& a, float h, const float4& w) {
    a.x = fmaf(h, w.x, a.x); a.y = fmaf(h, w.y, a.y);
    a.z = fmaf(h, w.z, a.z); a.w = fmaf(h, w.w, a.w);
}

// exact A2 hex lattice nearest-point quantizer; matches jnp.round (rint = RNE)
__device__ __forceinline__ void hexq(float p0, float p1, float& q0, float& q1) {
    const float S3 = 1.7320508075688772f;
    const float H3 = 0.8660254037844386f;
    float c00 = rintf(p0);
    float c01 = rintf(p1 / S3) * S3;
    float c10 = rintf(p0 - 0.5f) + 0.5f;
    float c11 = rintf((p1 - H3) / S3) * S3 + H3;
    float d0 = (p0 - c00) * (p0 - c00) + (p1 - c01) * (p1 - c01);
    float d1 = (p0 - c10) * (p0 - c10) + (p1 - c11) * (p1 - c11);
    bool take0 = d0 <= d1;
    q0 = take0 ? c00 : c10;
    q1 = take0 ? c01 : c11;
}

// per-channel prior chain: log(pdf + 1e-9) at point p, params P (58 floats)
__device__ __forceinline__ float logpdf_ch(const float* __restrict__ P, float p) {
    float w00 = P[0], w01 = P[1], w02 = P[2];
    float z0 = fmaf(w00, p, P[3]);
    float z1 = fmaf(w01, p, P[4]);
    float z2 = fmaf(w02, p, P[5]);
    float a0 = P[6], a1 = P[7], a2 = P[8];
    float e0 = tanh_fast(z0), e1 = tanh_fast(z1), e2 = tanh_fast(z2);
    float h0 = fmaf(a0, e0, z0), h1 = fmaf(a1, e1, z1), h2 = fmaf(a2, e2, z2);
    float t0 = w00 * fmaf(a0, fmaf(-e0, e0, 1.f), 1.f);
    float t1 = w01 * fmaf(a1, fmaf(-e1, e1, 1.f), 1.f);
    float t2 = w02 * fmaf(a2, fmaf(-e2, e2, 1.f), 1.f);

#define EB_LAYER(O)                                                            \
    {                                                                          \
        float z0n = fmaf(P[O+0], h0, fmaf(P[O+1], h1, fmaf(P[O+2], h2, P[O+9])));  \
        float z1n = fmaf(P[O+3], h0, fmaf(P[O+4], h1, fmaf(P[O+5], h2, P[O+10]))); \
        float z2n = fmaf(P[O+6], h0, fmaf(P[O+7], h1, fmaf(P[O+8], h2, P[O+11]))); \
        float s0 = fmaf(P[O+0], t0, fmaf(P[O+1], t1, P[O+2] * t2));            \
        float s1 = fmaf(P[O+3], t0, fmaf(P[O+4], t1, P[O+5] * t2));            \
        float s2 = fmaf(P[O+6], t0, fmaf(P[O+7], t1, P[O+8] * t2));            \
        float g0 = P[O+12], g1 = P[O+13], g2 = P[O+14];                        \
        float q0 = tanh_fast(z0n), q1 = tanh_fast(z1n), q2 = tanh_fast(z2n);   \
        h0 = fmaf(g0, q0, z0n); h1 = fmaf(g1, q1, z1n); h2 = fmaf(g2, q2, z2n); \
        t0 = s0 * fmaf(g0, fmaf(-q0, q0, 1.f), 1.f);                           \
        t1 = s1 * fmaf(g1, fmaf(-q1, q1, 1.f), 1.f);                           \
        t2 = s2 * fmaf(g2, fmaf(-q2, q2, 1.f), 1.f);                           \
    }
    EB_LAYER(9)
    EB_LAYER(24)
    EB_LAYER(39)
#undef EB_LAYER

    float L = fmaf(P[54], h0, fmaf(P[55], h1, fmaf(P[56], h2, P[57])));
    float T = fmaf(P[54], t0, fmaf(P[55], t1, P[56] * t2));
    float Lc = fminf(fmaxf(L, -30.f), 30.f);
    float sg = rcp_fast(1.f + __expf(-Lc));
    float pdf = sg * (1.f - sg) * T;
    return __logf(pdf + 1e-9f);
}

// ---------------------------------------------------------------------------
// K0: precompute prior params, u2^T, and init kmm
// ---------------------------------------------------------------------------
__global__ __launch_bounds__(256) void k_prep(
    const float* __restrict__ H0p, const float* __restrict__ H1p,
    const float* __restrict__ H2p, const float* __restrict__ H3p,
    const float* __restrict__ H4p,
    const float* __restrict__ b0p, const float* __restrict__ b1p,
    const float* __restrict__ b2p, const float* __restrict__ b3p,
    const float* __restrict__ b4p,
    const float* __restrict__ a0p, const float* __restrict__ a1p,
    const float* __restrict__ a2p, const float* __restrict__ a3p,
    const float* __restrict__ u, float* __restrict__ eb, float* __restrict__ u2t,
    int* __restrict__ kmm)
{
    int tid = threadIdx.x;
    if (tid < 24) {
        int c = tid;
        float* P = eb + c * 58;
        for (int j = 0; j < 3; ++j) P[j]      = splus_precise(H0p[c*3+j]);
        for (int j = 0; j < 3; ++j) P[3+j]    = b0p[c*3+j];
        for (int j = 0; j < 3; ++j) P[6+j]    = tanhf(a0p[c*3+j]);
        for (int j = 0; j < 9; ++j) P[9+j]    = splus_precise(H1p[c*9+j]);
        for (int j = 0; j < 3; ++j) P[18+j]   = b1p[c*3+j];
        for (int j = 0; j < 3; ++j) P[21+j]   = tanhf(a1p[c*3+j]);
        for (int j = 0; j < 9; ++j) P[24+j]   = splus_precise(H2p[c*9+j]);
        for (int j = 0; j < 3; ++j) P[33+j]   = b2p[c*3+j];
        for (int j = 0; j < 3; ++j) P[36+j]   = tanhf(a2p[c*3+j]);
        for (int j = 0; j < 9; ++j) P[39+j]   = splus_precise(H3p[c*9+j]);
        for (int j = 0; j < 3; ++j) P[48+j]   = b3p[c*3+j];
        for (int j = 0; j < 3; ++j) P[51+j]   = tanhf(a3p[c*3+j]);
        for (int j = 0; j < 3; ++j) P[54+j]   = splus_precise(H4p[c*3+j]);
        P[57] = b4p[c];
        kmm[tid]      = INT_MAX;
        kmm[24 + tid] = INT_MIN;
    }
    int m = tid;
    if (m < 256) {
        for (int j = 0; j < 12; ++j) {
            float a  = u[m*24 + 2*j];
            float bb = u[m*24 + 2*j + 1];
            float p0 = fmaf(0.5f, bb, a);
            float p1 = 0.8660254037844386f * bb;
            float q0, q1; hexq(p0, p1, q0, q1);
            u2t[(2*j)   * 256 + m] = p0 - q0;
            u2t[(2*j+1) * 256 + m] = p1 - q1;
        }
    }
}

// ---------------------------------------------------------------------------
// K1/K4: 2 -> 100 (lrelu) -> 100 (lrelu) -> 2 as a register-tiled GEMM.
// 64 rows/block, 256 threads. W1 transposed + XOR-swizzled in LDS; h0^T in
// LDS. Thread tile = 8 rows x 4 cols; per k: 3 ds_read_b128 + 32 FMA, no
// shuffles. Layer-2 (100->2) reduced once via LDS tree (fixed order).
// MEAN=1: per-block channel partial sums for the EMA mean.
// ---------------------------------------------------------------------------
template <int MEAN>
__global__ __launch_bounds__(256, 2) void k_gemm2(
    const float* __restrict__ in,
    const float* __restrict__ w0, const float* __restrict__ b0,
    const float* __restrict__ w1, const float* __restrict__ b1,
    const float* __restrict__ w2, const float* __restrict__ b2,
    float* __restrict__ out, float* __restrict__ partial)
{
    __shared__ alignas(16) float sw1[100 * 128];  // w1T swizzled [j][i]
    __shared__ alignas(16) float shT[100 * 64];   // h0T [j][row]
    __shared__ float sw0[200], sb0[100];
    __shared__ alignas(16) float sb1[128];
    __shared__ alignas(16) float sw2[2 * 128];
    __shared__ float sb2v[2];
    __shared__ float S[64][2];

    int tid = threadIdx.x;
    int row0 = blockIdx.x * 64;

    // ---- stage W1 transposed, float4-group XOR swizzle: grp ^= (j & 31) ----
    for (int idx = tid; idx < 10000; idx += 256) {
        int i = idx / 100, j = idx - i * 100;   // w1[i][j]
        int g = (i >> 2) ^ (j & 31);
        sw1[j * 128 + g * 4 + (i & 3)] = w1[idx];
    }
    for (int idx = tid; idx < 2800; idx += 256) {  // zero-pad i = 100..127
        int j = idx / 28, i = 100 + (idx - j * 28);
        int g = (i >> 2) ^ (j & 31);
        sw1[j * 128 + g * 4 + (i & 3)] = 0.f;
    }
    for (int t = tid; t < 200; t += 256) sw0[t] = w0[t];
    for (int t = tid; t < 100; t += 256) sb0[t] = b0[t];
    for (int t = tid; t < 128; t += 256) sb1[t] = (t < 100) ? b1[t] : 0.f;
    {
        int p = tid >> 7, c = tid & 127;
        sw2[tid] = (c < 100) ? w2[p * 100 + c] : 0.f;
    }
    if (tid < 2) sb2v[tid] = b2[tid];
    __syncthreads();

    // ---- layer 0: h0T[j][row] ----
    int lrow = tid & 63, jg = tid >> 6;
    float2 xv = ((const float2*)in)[row0 + lrow];
#pragma unroll
    for (int jj = 0; jj < 25; ++jj) {
        int j = jg * 25 + jj;
        shT[j * 64 + lrow] =
            lrelu(fmaf(sw0[2*j], xv.x, fmaf(sw0[2*j+1], xv.y, sb0[j])));
    }
    __syncthreads();

    // ---- k-loop: 8 rows x 4 cols per thread ----
    int lane = tid & 63, wv = tid >> 6;
    int ct = lane & 31;
    int rt = wv * 2 + (lane >> 5);
    float4 acc[8];
#pragma unroll
    for (int r = 0; r < 8; ++r) acc[r] = make_float4(0.f, 0.f, 0.f, 0.f);
    const float4* hT4 = (const float4*)shT;     // [100][16]
    const float4* w1T4 = (const float4*)sw1;    // [100][32] swizzled
#pragma unroll 2
    for (int k = 0; k < 100; ++k) {
        float4 w4 = w1T4[k * 32 + (ct ^ (k & 31))];
        float4 ha = hT4[k * 16 + rt * 2];
        float4 hb = hT4[k * 16 + rt * 2 + 1];
        fma4(acc[0], ha.x, w4); fma4(acc[1], ha.y, w4);
        fma4(acc[2], ha.z, w4); fma4(acc[3], ha.w, w4);
        fma4(acc[4], hb.x, w4); fma4(acc[5], hb.y, w4);
        fma4(acc[6], hb.z, w4); fma4(acc[7], hb.w, w4);
    }
    __syncthreads();          // all reads of sw1 done; reuse as reduction pad

    // ---- layer 1 activation + layer 2 partials ----
    float* red = sw1;         // [64][2][32]
    float4 b14 = ((const float4*)sb1)[ct];
    float4 w20 = ((const float4*)sw2)[ct];
    float4 w21 = ((const float4*)sw2)[32 + ct];
#pragma unroll
    for (int r = 0; r < 8; ++r) {
        float a0 = lrelu(acc[r].x + b14.x);
        float a1 = lrelu(acc[r].y + b14.y);
        float a2 = lrelu(acc[r].z + b14.z);
        float a3 = lrelu(acc[r].w + b14.w);
        float y0 = fmaf(a0, w20.x, fmaf(a1, w20.y, fmaf(a2, w20.z, a3 * w20.w)));
        float y1 = fmaf(a0, w21.x, fmaf(a1, w21.y, fmaf(a2, w21.z, a3 * w21.w)));
        int row = rt * 8 + r;
        red[(row * 2) * 32 + ct]     = y0;
        red[(row * 2 + 1) * 32 + ct] = y1;
    }
    __syncthreads();
    if (tid < 128) {
        int row = tid >> 1, p = tid & 1;
        const float4* rp = (const float4*)&red[(row * 2 + p) * 32];
        float s = 0.f;
#pragma unroll
        for (int g = 0; g < 8; ++g) {
            float4 v = rp[g];
            s += (v.x + v.y) + (v.z + v.w);
        }
        float y = s + sb2v[p];
        out[(row0 + row) * 2 + p] = y;
        if (MEAN) S[row][p] = y;
    }
    if (MEAN) {
        __syncthreads();
        if (tid < 24) {
            int j = tid >> 1, par = tid & 1;
            int base = row0 % 12;
            int k0 = (j - base + 12) % 12;
            float s = 0.f;
            for (int k = k0; k < 64; k += 12) s += S[k][par];
            partial[blockIdx.x * 24 + tid] = s;
        }
    }
}

// ---------------------------------------------------------------------------
// K2: finish the EMA mean from 768 per-block partials (1 block, sub-us)
// ---------------------------------------------------------------------------
__global__ __launch_bounds__(256) void k_mean_final(
    const float* __restrict__ partial, const float* __restrict__ y_mean,
    float* __restrict__ ym)
{
    int tid = threadIdx.x;
    int c = tid >> 3, s = tid & 7;
    float v = 0.f;
    if (c < 24)
        for (int g = s; g < G2_BLOCKS; g += 8) v += partial[g * 24 + c];
    v += __shfl_xor(v, 1); v += __shfl_xor(v, 2); v += __shfl_xor(v, 4);
    if (c < 24 && s == 0)
        ym[c] = fmaf(0.05f, y_mean[c], 0.95f * (v * (1.0f / NB)));
}

// ---------------------------------------------------------------------------
// K3: 24 -> 100 (softplus) -> 100 (softplus) -> 24, GEMM-tiled like k_gemm2.
// 32 rows/block, 128 blocks, thread tile 4 rows x 4 cols.
// MODE 0: input = y1 - ym, output = hexq(...) -> yhat, + kmm atomics
// MODE 1: input = yhat,    output = mlp + ym  -> yhat1
// ---------------------------------------------------------------------------
template <int MODE>
__global__ __launch_bounds__(256, 2) void k_mlp24g(
    const float* __restrict__ in,
    const float* __restrict__ w0, const float* __restrict__ w1,
    const float* __restrict__ w2,
    const float* __restrict__ ymg, float* __restrict__ out,
    int* __restrict__ kmm)
{
    __shared__ alignas(16) float sw1[100 * 128];  // w1T swizzled
    __shared__ alignas(16) float shT[100 * 32];   // h0T, reused as h1T
    __shared__ float sX[32 * 25];
    __shared__ float sO[32 * 25];
    __shared__ int kminL[24], kmaxL[24];

    int tid = threadIdx.x;
    int row0 = blockIdx.x * 32;

    for (int idx = tid; idx < 10000; idx += 256) {
        int i = idx / 100, j = idx - i * 100;
        int g = (i >> 2) ^ (j & 31);
        sw1[j * 128 + g * 4 + (i & 3)] = w1[idx];
    }
    for (int idx = tid; idx < 2800; idx += 256) {
        int j = idx / 28, i = 100 + (idx - j * 28);
        int g = (i >> 2) ^ (j & 31);
        sw1[j * 128 + g * 4 + (i & 3)] = 0.f;
    }
    for (int t = tid; t < 768; t += 256) {
        int r = t / 24, c = t - r * 24;
        float v = in[row0 * 24 + t];
        if (MODE == 0) v -= ymg[c];
        sX[r * 25 + c] = v;
    }
    if (MODE == 0 && tid < 24) { kminL[tid] = INT_MAX; kmaxL[tid] = INT_MIN; }
    __syncthreads();

    // layer 0: h0T[j][row], j uniform per half-wave -> w0 reads broadcast
    for (int idx = tid; idx < 3200; idx += 256) {
        int j = idx >> 5, row = idx & 31;
        const float* wr = w0 + j * 24;
        const float* xr = sX + row * 25;
        float a = 0.f, b = 0.f;
#pragma unroll
        for (int kk = 0; kk < 24; kk += 2) {
            a = fmaf(wr[kk],     xr[kk],     a);
            b = fmaf(wr[kk + 1], xr[kk + 1], b);
        }
        shT[j * 32 + row] = splus(a + b);
    }
    __syncthreads();

    // k-loop: 4 rows x 4 cols per thread
    int lane = tid & 63, wv = tid >> 6;
    int ct = lane & 31;
    int rt = wv * 2 + (lane >> 5);   // 0..7 -> rows rt*4..+3
    float4 acc[4];
#pragma unroll
    for (int r = 0; r < 4; ++r) acc[r] = make_float4(0.f, 0.f, 0.f, 0.f);
    const float4* hT4 = (const float4*)shT;     // [100][8]
    const float4* w1T4 = (const float4*)sw1;
#pragma unroll 2
    for (int k = 0; k < 100; ++k) {
        float4 w4 = w1T4[k * 32 + (ct ^ (k & 31))];
        float4 h4 = hT4[k * 8 + rt];
        fma4(acc[0], h4.x, w4); fma4(acc[1], h4.y, w4);
        fma4(acc[2], h4.z, w4); fma4(acc[3], h4.w, w4);
    }
    __syncthreads();   // before overwriting shT with h1T

    int i0 = ct * 4;
#pragma unroll
    for (int rr = 0; rr < 4; ++rr) {
        int row = rt * 4 + rr;
        if (i0 < 100)     shT[(i0    ) * 32 + row] = splus(acc[rr].x);
        if (i0 + 1 < 100) shT[(i0 + 1) * 32 + row] = splus(acc[rr].y);
        if (i0 + 2 < 100) shT[(i0 + 2) * 32 + row] = splus(acc[rr].z);
        if (i0 + 3 < 100) shT[(i0 + 3) * 32 + row] = splus(acc[rr].w);
    }
    __syncthreads();

    // layer 2: out[row][oc], oc uniform per half-wave -> w2 reads broadcast
    for (int idx = tid; idx < 768; idx += 256) {
        int oc = idx >> 5, row = idx & 31;
        const float* w2r = w2 + oc * 100;
        float s = 0.f, s2 = 0.f;
#pragma unroll 4
        for (int i = 0; i < 100; i += 2) {
            s  = fmaf(w2r[i],     shT[i * 32 + row],       s);
            s2 = fmaf(w2r[i + 1], shT[(i + 1) * 32 + row], s2);
        }
        float v = s + s2;
        if (MODE == 0) sO[row * 25 + oc] = v;
        else out[(row0 + row) * 24 + oc] = v + ymg[oc];
    }
    if (MODE == 0) {
        __syncthreads();
        for (int idx = tid; idx < 384; idx += 256) {
            int pr = idx >> 5, row = idx & 31;
            float v0 = sO[row * 25 + 2 * pr], v1 = sO[row * 25 + 2 * pr + 1];
            float q0, q1; hexq(v0, v1, q0, q1);
            out[(row0 + row) * 24 + 2 * pr]     = q0;
            out[(row0 + row) * 24 + 2 * pr + 1] = q1;
            int k0 = (int)rintf(q0 * 2.0f);
            int k1 = (int)rintf(q1 * INV_ODD);
            atomicMin(&kminL[2 * pr], k0);     atomicMax(&kmaxL[2 * pr], k0);
            atomicMin(&kminL[2 * pr + 1], k1); atomicMax(&kmaxL[2 * pr + 1], k1);
        }
        __syncthreads();
        if (tid < 24) {
            atomicMin(&kmm[tid], kminL[tid]);
            atomicMax(&kmm[24 + tid], kmaxL[tid]);
        }
    }
}

// ---------------------------------------------------------------------------
// K5b: build T[c][v][m] = logpdf_c((kmin_c+v)*step_c + u2[c,m]); grid 24*64
// ---------------------------------------------------------------------------
__global__ __launch_bounds__(256) void k_table(
    const float* __restrict__ eb, const float* __restrict__ u2t,
    const int* __restrict__ kmm, float* __restrict__ tbl)
{
    int cv = blockIdx.x;
    int c = cv >> 6, v = cv & 63;
    int m = threadIdx.x;
    float step = (c & 1) ? STEP_ODD : 0.5f;
    float val = (float)(kmm[c] + v) * step;
    float p = val + u2t[c * 256 + m];
    tbl[cv * 256 + m] = logpdf_ch(eb + c * 58, p);
}

// ---------------------------------------------------------------------------
// K5c: MC likelihood via table gather; shuffle-based logsumexp.
// ---------------------------------------------------------------------------
__global__ __launch_bounds__(256) void k_mc_tbl(
    const float* __restrict__ yhat, const float* __restrict__ u2t,
    const float* __restrict__ eb, const int* __restrict__ kmm,
    const float* __restrict__ tbl, float* __restrict__ lik)
{
    __shared__ float redm[4], reds[4];
    int tid = threadIdx.x;
    int wv = tid >> 6;
    int b = blockIdx.x;

    float y[24];
    const float4* yr = (const float4*)(yhat + b * 24);
#pragma unroll
    for (int k4 = 0; k4 < 6; ++k4) {
        float4 t = yr[k4];
        y[4*k4] = t.x; y[4*k4+1] = t.y; y[4*k4+2] = t.z; y[4*k4+3] = t.w;
    }

    float lp = 0.f;
    unsigned miss = 0;
#pragma unroll
    for (int c = 0; c < 24; ++c) {
        float inv = (c & 1) ? INV_ODD : 2.0f;
        int k = (int)rintf(y[c] * inv);
        int idx = k - kmm[c];
        if (idx >= 0 && idx < 64)
            lp += tbl[(c * 64 + idx) * 256 + tid];
        else
            miss |= (1u << c);
    }
    while (miss) {   // rare fallback: channel exceeded 64 lattice slots
        int c = __ffs(miss) - 1;
        miss &= miss - 1;
        lp += logpdf_ch(eb + c * 58, y[c] + u2t[c * 256 + tid]);
    }

    float m = lp;
#pragma unroll
    for (int off = 1; off < 64; off <<= 1) m = fmaxf(m, __shfl_xor(m, off));
    if ((tid & 63) == 0) redm[wv] = m;
    __syncthreads();
    float mx = fmaxf(fmaxf(redm[0], redm[1]), fmaxf(redm[2], redm[3]));
    float e = __expf(lp - mx);
#pragma unroll
    for (int off = 1; off < 64; off <<= 1) e += __shfl_xor(e, off);
    if ((tid & 63) == 0) reds[wv] = e;
    __syncthreads();
    if (tid == 0)
        lik[b] = mx + __logf(reds[0] + reds[1] + reds[2] + reds[3])
               - 7.271269879190247f;  // -log(NMC) + LOG_VOL
}

// ---------------------------------------------------------------------------
// K5 fallback (ws too small): direct MC
// ---------------------------------------------------------------------------
__global__ __launch_bounds__(256) void k_mc_direct(
    const float* __restrict__ yhat, const float* __restrict__ u2t,
    const float* __restrict__ eb, float* __restrict__ lik)
{
    __shared__ alignas(16) float sU[24 * 256];
    __shared__ float redm[4], reds[4];
    int tid = threadIdx.x;
    int wv = tid >> 6;
    int b = blockIdx.x;
    for (int i = tid; i < 1536; i += 256)
        ((float4*)sU)[i] = ((const float4*)u2t)[i];
    __syncthreads();

    float lp = 0.f;
    for (int c = 0; c < 24; ++c)
        lp += logpdf_ch(eb + c * 58, yhat[b * 24 + c] + sU[c * 256 + tid]);

    float m = lp;
#pragma unroll
    for (int off = 1; off < 64; off <<= 1) m = fmaxf(m, __shfl_xor(m, off));
    if ((tid & 63) == 0) redm[wv] = m;
    __syncthreads();
    float mx = fmaxf(fmaxf(redm[0], redm[1]), fmaxf(redm[2], redm[3]));
    float e = __expf(lp - mx);
#pragma unroll
    for (int off = 1; off < 64; off <<= 1) e += __shfl_xor(e, off);
    if ((tid & 63) == 0) reds[wv] = e;
    __syncthreads();
    if (tid == 0)
        lik[b] = mx + __logf(reds[0] + reds[1] + reds[2] + reds[3])
               - 7.271269879190247f;
}

// ---------------------------------------------------------------------------
extern "C" void kernel_launch(void* const* d_in, const int* in_sizes, int n_in,
                              void* d_out, int out_size, void* d_ws, size_t ws_size,
                              hipStream_t stream)
{
    (void)in_sizes; (void)n_in; (void)out_size;
    const float* x      = (const float*)d_in[0];
    const float* y_mean = (const float*)d_in[1];
    const float* u      = (const float*)d_in[2];
    const float* ga_w0  = (const float*)d_in[3];
    const float* ga_b0  = (const float*)d_in[4];
    const float* ga_w1  = (const float*)d_in[5];
    const float* ga_b1  = (const float*)d_in[6];
    const float* ga_w2  = (const float*)d_in[7];
    const float* ga_b2  = (const float*)d_in[8];
    const float* gs_w0  = (const float*)d_in[9];
    const float* gs_b0  = (const float*)d_in[10];
    const float* gs_w1  = (const float*)d_in[11];
    const float* gs_b1  = (const float*)d_in[12];
    const float* gs_w2  = (const float*)d_in[13];
    const float* gs_b2  = (const float*)d_in[14];
    const float* gac_w0 = (const float*)d_in[15];
    const float* gac_w1 = (const float*)d_in[16];
    const float* gac_w2 = (const float*)d_in[17];
    const float* gsc_w0 = (const float*)d_in[18];
    const float* gsc_w1 = (const float*)d_in[19];
    const float* gsc_w2 = (const float*)d_in[20];
    const float* eb_H0  = (const float*)d_in[21];
    const float* eb_H1  = (const float*)d_in[22];
    const float* eb_H2  = (const float*)d_in[23];
    const float* eb_H3  = (const float*)d_in[24];
    const float* eb_H4  = (const float*)d_in[25];
    const float* eb_b0  = (const float*)d_in[26];
    const float* eb_b1  = (const float*)d_in[27];
    const float* eb_b2  = (const float*)d_in[28];
    const float* eb_b3  = (const float*)d_in[29];
    const float* eb_b4  = (const float*)d_in[30];
    const float* eb_a0  = (const float*)d_in[31];
    const float* eb_a1  = (const float*)d_in[32];
    const float* eb_a2  = (const float*)d_in[33];
    const float* eb_a3  = (const float*)d_in[34];

    float* ws    = (float*)d_ws;
    float* y1    = ws + WS_Y1;
    float* yhat  = ws + WS_YHAT;
    float* yhat1 = ws + WS_YHAT1;
    float* ym    = ws + WS_YM;
    float* u2t   = ws + WS_U2T;
    float* eb    = ws + WS_EB;
    int*   kmm   = (int*)(ws + WS_KMM);
    float* part  = ws + WS_PART;
    float* tbl   = ws + WS_TBL;
    float* xhat  = (float*)d_out;
    float* lik   = (float*)d_out + 98304;

    bool use_tbl = ws_size >= WS_END * sizeof(float);

    k_prep<<<1, 256, 0, stream>>>(eb_H0, eb_H1, eb_H2, eb_H3, eb_H4,
                                  eb_b0, eb_b1, eb_b2, eb_b3, eb_b4,
                                  eb_a0, eb_a1, eb_a2, eb_a3, u, eb, u2t, kmm);
    k_gemm2<1><<<G2_BLOCKS, 256, 0, stream>>>(x, ga_w0, ga_b0, ga_w1, ga_b1,
                                              ga_w2, ga_b2, y1, part);
    k_mean_final<<<1, 256, 0, stream>>>(part, y_mean, ym);
    k_mlp24g<0><<<NB / 32, 256, 0, stream>>>(y1, gac_w0, gac_w1, gac_w2, ym,
                                             yhat, kmm);
    if (use_tbl)
        k_table<<<24 * 64, 256, 0, stream>>>(eb, u2t, kmm, tbl);
    k_mlp24g<1><<<NB / 32, 256, 0, stream>>>(yhat, gsc_w0, gsc_w1, gsc_w2, ym,
                                             yhat1, kmm);
    k_gemm2<0><<<G2_BLOCKS, 256, 0, stream>>>(yhat1, gs_w0, gs_b0, gs_w1, gs_b1,
                                              gs_w2, gs_b2, xhat, nullptr);
    if (use_tbl)
        k_mc_tbl<<<NB, 256, 0, stream>>>(yhat, u2t, eb, kmm, tbl, lik);
    else
        k_mc_direct<<<NB, 256, 0, stream>>>(yhat, u2t, eb, lik);
}

// Round 6
// 143.483 us; speedup vs baseline: 1.3280x; 1.2415x over previous
//
#include <hip/hip_runtime.h>
#include <hip/hip_bf16.h>
#include <math.h>
#include <limits.h>

// Problem dims
constexpr int NB    = 4096;   // batch
constexpr int ROWS2 = NB * 12;            // 49152 rows for the 2->100->100->2 MLPs
constexpr int G2_BLOCKS = ROWS2 / 64;     // 768 (64 rows/block)
constexpr int TBL_CAP = 48;               // lattice slots per channel

// workspace layout (float offsets)
constexpr size_t WS_Y1    = 0;              // NB*24
constexpr size_t WS_YHAT  = 98304;          // NB*24
constexpr size_t WS_YHAT1 = 196608;         // NB*24
constexpr size_t WS_YM    = 294912;         // 24
constexpr size_t WS_U2T   = 294936;         // 24*256 (transposed: [c][m])
constexpr size_t WS_EB    = 301080;         // 24*58 precomputed prior params
constexpr size_t WS_KMM   = 302472;         // 48 ints (kmin[24], kmax[24])
constexpr size_t WS_PART  = 302520;         // 768*24 per-block mean partials
constexpr size_t WS_W1T   = 320952;         // 4 x [100][128] transposed w1 (51200)
constexpr size_t WS_TBL   = 372152;         // 24*48*256 table of log(pdf+1e-9)
constexpr size_t WS_END   = WS_TBL + 24 * TBL_CAP * 256;   // 667064 floats (~2.67 MB)

constexpr float STEP_ODD = 0.8660254037844386f;   // sqrt(3)/2
constexpr float INV_ODD  = 1.1547005383792517f;   // 2/sqrt(3)

__device__ __forceinline__ float lrelu(float x) { return x >= 0.f ? x : 0.01f * x; }
__device__ __forceinline__ float rcp_fast(float x) { return __builtin_amdgcn_rcpf(x); }

__device__ __forceinline__ float tanh_fast(float x) {
    float xx = fminf(fmaxf(x, -15.f), 15.f);
    float e = __expf(xx + xx);
    return fmaf(-2.f, rcp_fast(e + 1.f), 1.f);
}
__device__ __forceinline__ float splus(float x) {
    return fmaxf(x, 0.f) + __logf(1.f + __expf(-fabsf(x)));
}
__device__ __forceinline__ float splus_precise(float x) {
    return fmaxf(x, 0.f) + log1pf(expf(-fabsf(x)));
}

__device__ __forceinline__ void fma4(float4& a, float h, const float4& w) {
    a.x = fmaf(h, w.x, a.x); a.y = fmaf(h, w.y, a.y);
    a.z = fmaf(h, w.z, a.z); a.w = fmaf(h, w.w, a.w);
}

// exact A2 hex lattice nearest-point quantizer; matches jnp.round (rint = RNE)
__device__ __forceinline__ void hexq(float p0, float p1, float& q0, float& q1) {
    const float S3 = 1.7320508075688772f;
    const float H3 = 0.8660254037844386f;
    float c00 = rintf(p0);
    float c01 = rintf(p1 / S3) * S3;
    float c10 = rintf(p0 - 0.5f) + 0.5f;
    float c11 = rintf((p1 - H3) / S3) * S3 + H3;
    float d0 = (p0 - c00) * (p0 - c00) + (p1 - c01) * (p1 - c01);
    float d1 = (p0 - c10) * (p0 - c10) + (p1 - c11) * (p1 - c11);
    bool take0 = d0 <= d1;
    q0 = take0 ? c00 : c10;
    q1 = take0 ? c01 : c11;
}

// per-channel prior chain: log(pdf + 1e-9) at point p, params P (58 floats)
__device__ __forceinline__ float logpdf_ch(const float* __restrict__ P, float p) {
    float w00 = P[0], w01 = P[1], w02 = P[2];
    float z0 = fmaf(w00, p, P[3]);
    float z1 = fmaf(w01, p, P[4]);
    float z2 = fmaf(w02, p, P[5]);
    float a0 = P[6], a1 = P[7], a2 = P[8];
    float e0 = tanh_fast(z0), e1 = tanh_fast(z1), e2 = tanh_fast(z2);
    float h0 = fmaf(a0, e0, z0), h1 = fmaf(a1, e1, z1), h2 = fmaf(a2, e2, z2);
    float t0 = w00 * fmaf(a0, fmaf(-e0, e0, 1.f), 1.f);
    float t1 = w01 * fmaf(a1, fmaf(-e1, e1, 1.f), 1.f);
    float t2 = w02 * fmaf(a2, fmaf(-e2, e2, 1.f), 1.f);

#define EB_LAYER(O)                                                            \
    {                                                                          \
        float z0n = fmaf(P[O+0], h0, fmaf(P[O+1], h1, fmaf(P[O+2], h2, P[O+9])));  \
        float z1n = fmaf(P[O+3], h0, fmaf(P[O+4], h1, fmaf(P[O+5], h2, P[O+10]))); \
        float z2n = fmaf(P[O+6], h0, fmaf(P[O+7], h1, fmaf(P[O+8], h2, P[O+11]))); \
        float s0 = fmaf(P[O+0], t0, fmaf(P[O+1], t1, P[O+2] * t2));            \
        float s1 = fmaf(P[O+3], t0, fmaf(P[O+4], t1, P[O+5] * t2));            \
        float s2 = fmaf(P[O+6], t0, fmaf(P[O+7], t1, P[O+8] * t2));            \
        float g0 = P[O+12], g1 = P[O+13], g2 = P[O+14];                        \
        float q0 = tanh_fast(z0n), q1 = tanh_fast(z1n), q2 = tanh_fast(z2n);   \
        h0 = fmaf(g0, q0, z0n); h1 = fmaf(g1, q1, z1n); h2 = fmaf(g2, q2, z2n); \
        t0 = s0 * fmaf(g0, fmaf(-q0, q0, 1.f), 1.f);                           \
        t1 = s1 * fmaf(g1, fmaf(-q1, q1, 1.f), 1.f);                           \
        t2 = s2 * fmaf(g2, fmaf(-q2, q2, 1.f), 1.f);                           \
    }
    EB_LAYER(9)
    EB_LAYER(24)
    EB_LAYER(39)
#undef EB_LAYER

    float L = fmaf(P[54], h0, fmaf(P[55], h1, fmaf(P[56], h2, P[57])));
    float T = fmaf(P[54], t0, fmaf(P[55], t1, P[56] * t2));
    float Lc = fminf(fmaxf(L, -30.f), 30.f);
    float sg = rcp_fast(1.f + __expf(-Lc));
    float pdf = sg * (1.f - sg) * T;
    return __logf(pdf + 1e-9f);
}

// ---------------------------------------------------------------------------
// K0: block 0: prior params + u2^T + kmm init.
//     blocks 1..200: transpose the four 100x100 W1 matrices into [100][128]
//     zero-padded layout (w1t[m][k*128 + i] = w1[m][i*100 + k]).
// ---------------------------------------------------------------------------
__global__ __launch_bounds__(256) void k_prep(
    const float* __restrict__ H0p, const float* __restrict__ H1p,
    const float* __restrict__ H2p, const float* __restrict__ H3p,
    const float* __restrict__ H4p,
    const float* __restrict__ b0p, const float* __restrict__ b1p,
    const float* __restrict__ b2p, const float* __restrict__ b3p,
    const float* __restrict__ b4p,
    const float* __restrict__ a0p, const float* __restrict__ a1p,
    const float* __restrict__ a2p, const float* __restrict__ a3p,
    const float* __restrict__ u,
    const float* __restrict__ w1ga, const float* __restrict__ w1gac,
    const float* __restrict__ w1gsc, const float* __restrict__ w1gs,
    float* __restrict__ eb, float* __restrict__ u2t,
    int* __restrict__ kmm, float* __restrict__ w1t)
{
    int tid = threadIdx.x;
    if (blockIdx.x > 0) {
        int t = blockIdx.x - 1;             // 0..199
        int m = t / 50;
        int o = (t % 50) * 256 + tid;       // 0..12799
        int k = o >> 7, i = o & 127;
        const float* src = (m == 0) ? w1ga : (m == 1) ? w1gac
                         : (m == 2) ? w1gsc : w1gs;
        w1t[m * 12800 + o] = (i < 100) ? src[i * 100 + k] : 0.f;
        return;
    }
    if (tid < 24) {
        int c = tid;
        float* P = eb + c * 58;
        for (int j = 0; j < 3; ++j) P[j]      = splus_precise(H0p[c*3+j]);
        for (int j = 0; j < 3; ++j) P[3+j]    = b0p[c*3+j];
        for (int j = 0; j < 3; ++j) P[6+j]    = tanhf(a0p[c*3+j]);
        for (int j = 0; j < 9; ++j) P[9+j]    = splus_precise(H1p[c*9+j]);
        for (int j = 0; j < 3; ++j) P[18+j]   = b1p[c*3+j];
        for (int j = 0; j < 3; ++j) P[21+j]   = tanhf(a1p[c*3+j]);
        for (int j = 0; j < 9; ++j) P[24+j]   = splus_precise(H2p[c*9+j]);
        for (int j = 0; j < 3; ++j) P[33+j]   = b2p[c*3+j];
        for (int j = 0; j < 3; ++j) P[36+j]   = tanhf(a2p[c*3+j]);
        for (int j = 0; j < 9; ++j) P[39+j]   = splus_precise(H3p[c*9+j]);
        for (int j = 0; j < 3; ++j) P[48+j]   = b3p[c*3+j];
        for (int j = 0; j < 3; ++j) P[51+j]   = tanhf(a3p[c*3+j]);
        for (int j = 0; j < 3; ++j) P[54+j]   = splus_precise(H4p[c*3+j]);
        P[57] = b4p[c];
        kmm[tid]      = INT_MAX;
        kmm[24 + tid] = INT_MIN;
    }
    int m = tid;
    if (m < 256) {
        for (int j = 0; j < 12; ++j) {
            float a  = u[m*24 + 2*j];
            float bb = u[m*24 + 2*j + 1];
            float p0 = fmaf(0.5f, bb, a);
            float p1 = 0.8660254037844386f * bb;
            float q0, q1; hexq(p0, p1, q0, q1);
            u2t[(2*j)   * 256 + m] = p0 - q0;
            u2t[(2*j+1) * 256 + m] = p1 - q1;
        }
    }
}

// ---------------------------------------------------------------------------
// K1/K4: 2 -> 100 (lrelu) -> 100 (lrelu) -> 2, register-tiled GEMM with
// weights streamed from L2 (pre-transposed w1t [100][128]) and ONLY h0^T in
// LDS (25.6 KB). 64 rows/block, 256 threads, thread tile 8 rows x 4 cols.
// Per k: 1 global b128 (coalesced, L2-hit) + 2 LDS b128 (broadcast) + 32 FMA.
// launch_bounds(256,4): VGPR<=128 -> 4 blocks/CU -> 16 waves/CU, grid 768 =
// one full round. MEAN=1: per-block channel partials for the EMA mean.
// ---------------------------------------------------------------------------
template <int MEAN>
__global__ __launch_bounds__(256, 4) void k_gemm2(
    const float* __restrict__ in,
    const float* __restrict__ w0, const float* __restrict__ b0,
    const float* __restrict__ w1t,
    const float* __restrict__ b1, const float* __restrict__ w2,
    const float* __restrict__ b2,
    float* __restrict__ out, float* __restrict__ partial)
{
    __shared__ alignas(16) float shT[100 * 64];   // h0T [k][row]; reused as red
    __shared__ float S[64][2];

    int tid = threadIdx.x;
    int row0 = blockIdx.x * 64;

    // layer 0: each wave computes a 25-wide j-slice for all 64 rows
    int lrow = tid & 63, jg = tid >> 6;
    float2 xv = ((const float2*)in)[row0 + lrow];
#pragma unroll
    for (int jj = 0; jj < 25; ++jj) {
        int j = jg * 25 + jj;
        shT[j * 64 + lrow] =
            lrelu(fmaf(w0[2*j], xv.x, fmaf(w0[2*j+1], xv.y, b0[j])));
    }

    int lane = tid & 63, wv = tid >> 6;
    int ct = lane & 31;                 // col group: cols 4ct..4ct+3 of 128
    int rt = wv * 2 + (lane >> 5);      // row group: rows 8rt..8rt+7
    bool cvalid = (4 * ct < 100);
    float4 zero4 = make_float4(0.f, 0.f, 0.f, 0.f);
    float4 b14 = cvalid ? *(const float4*)(b1 + 4*ct) : zero4;
    float4 w20 = cvalid ? *(const float4*)(w2 + 4*ct) : zero4;
    float4 w21 = cvalid ? *(const float4*)(w2 + 100 + 4*ct) : zero4;
    __syncthreads();

    float4 acc[8];
#pragma unroll
    for (int r = 0; r < 8; ++r) acc[r] = zero4;
    const float4* wg  = (const float4*)w1t + ct;   // +32 float4 per k
    const float4* hT4 = (const float4*)shT;        // [100][16]
#pragma unroll 4
    for (int k = 0; k < 100; ++k) {
        float4 w4 = wg[k * 32];
        float4 ha = hT4[k * 16 + rt * 2];
        float4 hb = hT4[k * 16 + rt * 2 + 1];
        fma4(acc[0], ha.x, w4); fma4(acc[1], ha.y, w4);
        fma4(acc[2], ha.z, w4); fma4(acc[3], ha.w, w4);
        fma4(acc[4], hb.x, w4); fma4(acc[5], hb.y, w4);
        fma4(acc[6], hb.z, w4); fma4(acc[7], hb.w, w4);
    }
    __syncthreads();          // h reads done; reuse shT as reduction pad

    float* red = shT;         // [64][2][32]
#pragma unroll
    for (int r = 0; r < 8; ++r) {
        float a0 = lrelu(acc[r].x + b14.x);
        float a1 = lrelu(acc[r].y + b14.y);
        float a2 = lrelu(acc[r].z + b14.z);
        float a3 = lrelu(acc[r].w + b14.w);
        float y0 = fmaf(a0, w20.x, fmaf(a1, w20.y, fmaf(a2, w20.z, a3 * w20.w)));
        float y1 = fmaf(a0, w21.x, fmaf(a1, w21.y, fmaf(a2, w21.z, a3 * w21.w)));
        int row = rt * 8 + r;
        red[(row * 2) * 32 + ct]     = y0;
        red[(row * 2 + 1) * 32 + ct] = y1;
    }
    __syncthreads();
    if (tid < 128) {
        int row = tid >> 1, p = tid & 1;
        const float4* rp = (const float4*)&red[(row * 2 + p) * 32];
        float s = 0.f;
#pragma unroll
        for (int g = 0; g < 8; ++g) {
            float4 v = rp[g];
            s += (v.x + v.y) + (v.z + v.w);
        }
        float y = s + b2[p];
        out[(row0 + row) * 2 + p] = y;
        if (MEAN) S[row][p] = y;
    }
    if (MEAN) {
        __syncthreads();
        if (tid < 24) {
            int j = tid >> 1, par = tid & 1;
            int base = row0 % 12;
            int k0 = (j - base + 12) % 12;
            float s = 0.f;
            for (int k = k0; k < 64; k += 12) s += S[k][par];
            partial[blockIdx.x * 24 + tid] = s;
        }
    }
}

// ---------------------------------------------------------------------------
// K2: finish the EMA mean from 768 per-block partials (1 block, sub-us)
// ---------------------------------------------------------------------------
__global__ __launch_bounds__(256) void k_mean_final(
    const float* __restrict__ partial, const float* __restrict__ y_mean,
    float* __restrict__ ym)
{
    int tid = threadIdx.x;
    int c = tid >> 3, s = tid & 7;
    float v = 0.f;
    if (c < 24)
        for (int g = s; g < G2_BLOCKS; g += 8) v += partial[g * 24 + c];
    v += __shfl_xor(v, 1); v += __shfl_xor(v, 2); v += __shfl_xor(v, 4);
    if (c < 24 && s == 0)
        ym[c] = fmaf(0.05f, y_mean[c], 0.95f * (v * (1.0f / NB)));
}

// ---------------------------------------------------------------------------
// K3: FUSED coupled transforms: yhat = hexq(gac(y1 - ym)), yhat1 = gsc(yhat)+ym.
// 16 rows/block, 256 blocks. W1 from L2 (transposed), w0/w2 staged in LDS.
// Layer-1 tile: 2 rows x 4 cols per thread (16 rows x 128 cols / 256 thr).
// ---------------------------------------------------------------------------
__global__ __launch_bounds__(256, 4) void k_fused24(
    const float* __restrict__ y1,
    const float* __restrict__ w0A, const float* __restrict__ w1tA,
    const float* __restrict__ w2A,
    const float* __restrict__ w0B, const float* __restrict__ w1tB,
    const float* __restrict__ w2B,
    const float* __restrict__ ymg,
    float* __restrict__ yhat, float* __restrict__ yhat1,
    int* __restrict__ kmm)
{
    __shared__ float sw0[100 * 25];          // padded [j][25]
    __shared__ float sw2[24 * 100];
    __shared__ float shA[100 * 18];          // h0 [k][row], pad 18
    __shared__ float shB[100 * 18];          // h1 [i][row], pad 18
    __shared__ float sX[16 * 25];
    __shared__ float sO[16 * 25];
    __shared__ float symL[24];
    __shared__ int kminL[24], kmaxL[24];

    int tid = threadIdx.x;
    int row0 = blockIdx.x * 16;
    if (tid < 24) {
        symL[tid] = ymg[tid];
        kminL[tid] = INT_MAX; kmaxL[tid] = INT_MIN;
    }
    for (int t = tid; t < 384; t += 256) {
        int r = t / 24, c = t - r * 24;
        sX[r * 25 + c] = y1[row0 * 24 + t] - ymg[c];
    }

    int lane = tid & 63, wv = tid >> 6;
    int ct = lane & 31;                 // cols 4ct..4ct+3
    int rt2 = wv * 2 + (lane >> 5);     // rows 2rt2, 2rt2+1

    for (int pass = 0; pass < 2; ++pass) {
        const float* w0  = pass ? w0B  : w0A;
        const float* w1t = pass ? w1tB : w1tA;
        const float* w2  = pass ? w2B  : w2A;
        for (int t = tid; t < 2400; t += 256) {
            int j = t / 24, kk = t - j * 24;
            sw0[j * 25 + kk] = w0[t];
            sw2[t] = w2[t];
        }
        __syncthreads();

        // layer 0: h0[j][row]
        for (int t = tid; t < 1600; t += 256) {
            int j = t >> 4, row = t & 15;
            const float* wr = sw0 + j * 25;
            const float* xr = sX + row * 25;
            float a = 0.f, b = 0.f;
#pragma unroll
            for (int kk = 0; kk < 24; kk += 2) {
                a = fmaf(wr[kk],     xr[kk],     a);
                b = fmaf(wr[kk + 1], xr[kk + 1], b);
            }
            shA[j * 18 + row] = splus(a + b);
        }
        __syncthreads();

        // layer 1: k-loop, weights from L2
        float4 acc0 = make_float4(0.f, 0.f, 0.f, 0.f), acc1 = acc0;
        const float4* wg = (const float4*)w1t + ct;
#pragma unroll 4
        for (int k = 0; k < 100; ++k) {
            float4 w4 = wg[k * 32];
            float2 h2 = *(const float2*)&shA[k * 18 + rt2 * 2];
            fma4(acc0, h2.x, w4);
            fma4(acc1, h2.y, w4);
        }
        // write h1 (cols are the new hidden index i)
        {
            int i0 = 4 * ct;
            float hv0[4] = {acc0.x, acc0.y, acc0.z, acc0.w};
            float hv1[4] = {acc1.x, acc1.y, acc1.z, acc1.w};
#pragma unroll
            for (int e = 0; e < 4; ++e) {
                int i = i0 + e;
                if (i < 100) {
                    shB[i * 18 + rt2 * 2]     = splus(hv0[e]);
                    shB[i * 18 + rt2 * 2 + 1] = splus(hv1[e]);
                }
            }
        }
        __syncthreads();

        // layer 2: out[row][oc]
        for (int t = tid; t < 384; t += 256) {
            int oc = t >> 4, row = t & 15;
            const float* w2r = sw2 + oc * 100;
            float s = 0.f, s2 = 0.f;
#pragma unroll 4
            for (int i = 0; i < 100; i += 2) {
                s  = fmaf(w2r[i],     shB[i * 18 + row],       s);
                s2 = fmaf(w2r[i + 1], shB[(i + 1) * 18 + row], s2);
            }
            float v = s + s2;
            if (pass == 0) sO[row * 25 + oc] = v;
            else yhat1[(row0 + row) * 24 + oc] = v + symL[oc];
        }

        if (pass == 0) {
            __syncthreads();
            for (int t = tid; t < 192; t += 256) {
                int row = t / 12, pr = t - row * 12;
                float v0 = sO[row * 25 + 2*pr], v1 = sO[row * 25 + 2*pr + 1];
                float q0, q1; hexq(v0, v1, q0, q1);
                yhat[(row0 + row) * 24 + 2*pr]     = q0;
                yhat[(row0 + row) * 24 + 2*pr + 1] = q1;
                sX[row * 25 + 2*pr]     = q0;     // pass-B input (no ym shift)
                sX[row * 25 + 2*pr + 1] = q1;
                int k0 = (int)rintf(q0 * 2.0f);
                int k1 = (int)rintf(q1 * INV_ODD);
                atomicMin(&kminL[2*pr], k0);     atomicMax(&kmaxL[2*pr], k0);
                atomicMin(&kminL[2*pr + 1], k1); atomicMax(&kmaxL[2*pr + 1], k1);
            }
            __syncthreads();
            if (tid < 24) {
                atomicMin(&kmm[tid], kminL[tid]);
                atomicMax(&kmm[24 + tid], kmaxL[tid]);
            }
        }
    }
}

// ---------------------------------------------------------------------------
// K5b: build T[c][v][m] = logpdf_c((kmin_c+v)*step_c + u2[c,m]); grid 24*48
// ---------------------------------------------------------------------------
__global__ __launch_bounds__(256) void k_table(
    const float* __restrict__ eb, const float* __restrict__ u2t,
    const int* __restrict__ kmm, float* __restrict__ tbl)
{
    int cv = blockIdx.x;
    int c = cv / TBL_CAP, v = cv - c * TBL_CAP;
    int m = threadIdx.x;
    float step = (c & 1) ? STEP_ODD : 0.5f;
    float val = (float)(kmm[c] + v) * step;
    float p = val + u2t[c * 256 + m];
    tbl[cv * 256 + m] = logpdf_ch(eb + c * 58, p);
}

// ---------------------------------------------------------------------------
// K5c: MC likelihood via table gather; shuffle-based logsumexp.
// ---------------------------------------------------------------------------
__global__ __launch_bounds__(256) void k_mc_tbl(
    const float* __restrict__ yhat, const float* __restrict__ u2t,
    const float* __restrict__ eb, const int* __restrict__ kmm,
    const float* __restrict__ tbl, float* __restrict__ lik)
{
    __shared__ float redm[4], reds[4];
    int tid = threadIdx.x;
    int wv = tid >> 6;
    int b = blockIdx.x;

    float y[24];
    const float4* yr = (const float4*)(yhat + b * 24);
#pragma unroll
    for (int k4 = 0; k4 < 6; ++k4) {
        float4 t = yr[k4];
        y[4*k4] = t.x; y[4*k4+1] = t.y; y[4*k4+2] = t.z; y[4*k4+3] = t.w;
    }

    float lp = 0.f;
    unsigned miss = 0;
#pragma unroll
    for (int c = 0; c < 24; ++c) {
        float inv = (c & 1) ? INV_ODD : 2.0f;
        int k = (int)rintf(y[c] * inv);
        int idx = k - kmm[c];
        if (idx >= 0 && idx < TBL_CAP)
            lp += tbl[(c * TBL_CAP + idx) * 256 + tid];
        else
            miss |= (1u << c);
    }
    while (miss) {   // rare fallback: channel exceeded TBL_CAP lattice slots
        int c = __ffs(miss) - 1;
        miss &= miss - 1;
        lp += logpdf_ch(eb + c * 58, y[c] + u2t[c * 256 + tid]);
    }

    float m = lp;
#pragma unroll
    for (int off = 1; off < 64; off <<= 1) m = fmaxf(m, __shfl_xor(m, off));
    if ((tid & 63) == 0) redm[wv] = m;
    __syncthreads();
    float mx = fmaxf(fmaxf(redm[0], redm[1]), fmaxf(redm[2], redm[3]));
    float e = __expf(lp - mx);
#pragma unroll
    for (int off = 1; off < 64; off <<= 1) e += __shfl_xor(e, off);
    if ((tid & 63) == 0) reds[wv] = e;
    __syncthreads();
    if (tid == 0)
        lik[b] = mx + __logf(reds[0] + reds[1] + reds[2] + reds[3])
               - 7.271269879190247f;  // -log(NMC) + LOG_VOL
}

// ---------------------------------------------------------------------------
// K5 fallback (ws too small): direct MC
// ---------------------------------------------------------------------------
__global__ __launch_bounds__(256) void k_mc_direct(
    const float* __restrict__ yhat, const float* __restrict__ u2t,
    const float* __restrict__ eb, float* __restrict__ lik)
{
    __shared__ alignas(16) float sU[24 * 256];
    __shared__ float redm[4], reds[4];
    int tid = threadIdx.x;
    int wv = tid >> 6;
    int b = blockIdx.x;
    for (int i = tid; i < 1536; i += 256)
        ((float4*)sU)[i] = ((const float4*)u2t)[i];
    __syncthreads();

    float lp = 0.f;
    for (int c = 0; c < 24; ++c)
        lp += logpdf_ch(eb + c * 58, yhat[b * 24 + c] + sU[c * 256 + tid]);

    float m = lp;
#pragma unroll
    for (int off = 1; off < 64; off <<= 1) m = fmaxf(m, __shfl_xor(m, off));
    if ((tid & 63) == 0) redm[wv] = m;
    __syncthreads();
    float mx = fmaxf(fmaxf(redm[0], redm[1]), fmaxf(redm[2], redm[3]));
    float e = __expf(lp - mx);
#pragma unroll
    for (int off = 1; off < 64; off <<= 1) e += __shfl_xor(e, off);
    if ((tid & 63) == 0) reds[wv] = e;
    __syncthreads();
    if (tid == 0)
        lik[b] = mx + __logf(reds[0] + reds[1] + reds[2] + reds[3])
               - 7.271269879190247f;
}

// ---------------------------------------------------------------------------
extern "C" void kernel_launch(void* const* d_in, const int* in_sizes, int n_in,
                              void* d_out, int out_size, void* d_ws, size_t ws_size,
                              hipStream_t stream)
{
    (void)in_sizes; (void)n_in; (void)out_size;
    const float* x      = (const float*)d_in[0];
    const float* y_mean = (const float*)d_in[1];
    const float* u      = (const float*)d_in[2];
    const float* ga_w0  = (const float*)d_in[3];
    const float* ga_b0  = (const float*)d_in[4];
    const float* ga_w1  = (const float*)d_in[5];
    const float* ga_b1  = (const float*)d_in[6];
    const float* ga_w2  = (const float*)d_in[7];
    const float* ga_b2  = (const float*)d_in[8];
    const float* gs_w0  = (const float*)d_in[9];
    const float* gs_b0  = (const float*)d_in[10];
    const float* gs_w1  = (const float*)d_in[11];
    const float* gs_b1  = (const float*)d_in[12];
    const float* gs_w2  = (const float*)d_in[13];
    const float* gs_b2  = (const float*)d_in[14];
    const float* gac_w0 = (const float*)d_in[15];
    const float* gac_w1 = (const float*)d_in[16];
    const float* gac_w2 = (const float*)d_in[17];
    const float* gsc_w0 = (const float*)d_in[18];
    const float* gsc_w1 = (const float*)d_in[19];
    const float* gsc_w2 = (const float*)d_in[20];
    const float* eb_H0  = (const float*)d_in[21];
    const float* eb_H1  = (const float*)d_in[22];
    const float* eb_H2  = (const float*)d_in[23];
    const float* eb_H3  = (const float*)d_in[24];
    const float* eb_H4  = (const float*)d_in[25];
    const float* eb_b0  = (const float*)d_in[26];
    const float* eb_b1  = (const float*)d_in[27];
    const float* eb_b2  = (const float*)d_in[28];
    const float* eb_b3  = (const float*)d_in[29];
    const float* eb_b4  = (const float*)d_in[30];
    const float* eb_a0  = (const float*)d_in[31];
    const float* eb_a1  = (const float*)d_in[32];
    const float* eb_a2  = (const float*)d_in[33];
    const float* eb_a3  = (const float*)d_in[34];

    float* ws    = (float*)d_ws;
    float* y1    = ws + WS_Y1;
    float* yhat  = ws + WS_YHAT;
    float* yhat1 = ws + WS_YHAT1;
    float* ym    = ws + WS_YM;
    float* u2t   = ws + WS_U2T;
    float* eb    = ws + WS_EB;
    int*   kmm   = (int*)(ws + WS_KMM);
    float* part  = ws + WS_PART;
    float* w1t   = ws + WS_W1T;
    float* tbl   = ws + WS_TBL;
    float* xhat  = (float*)d_out;
    float* lik   = (float*)d_out + 98304;

    float* w1tGA  = w1t;
    float* w1tGAC = w1t + 12800;
    float* w1tGSC = w1t + 25600;
    float* w1tGS  = w1t + 38400;

    bool use_tbl = ws_size >= WS_END * sizeof(float);

    k_prep<<<201, 256, 0, stream>>>(eb_H0, eb_H1, eb_H2, eb_H3, eb_H4,
                                    eb_b0, eb_b1, eb_b2, eb_b3, eb_b4,
                                    eb_a0, eb_a1, eb_a2, eb_a3, u,
                                    ga_w1, gac_w1, gsc_w1, gs_w1,
                                    eb, u2t, kmm, w1t);
    k_gemm2<1><<<G2_BLOCKS, 256, 0, stream>>>(x, ga_w0, ga_b0, w1tGA,
                                              ga_b1, ga_w2, ga_b2, y1, part);
    k_mean_final<<<1, 256, 0, stream>>>(part, y_mean, ym);
    k_fused24<<<NB / 16, 256, 0, stream>>>(y1, gac_w0, w1tGAC, gac_w2,
                                           gsc_w0, w1tGSC, gsc_w2,
                                           ym, yhat, yhat1, kmm);
    if (use_tbl)
        k_table<<<24 * TBL_CAP, 256, 0, stream>>>(eb, u2t, kmm, tbl);
    k_gemm2<0><<<G2_BLOCKS, 256, 0, stream>>>(yhat1, gs_w0, gs_b0, w1tGS,
                                              gs_b1, gs_w2, gs_b2, xhat, nullptr);
    if (use_tbl)
        k_mc_tbl<<<NB, 256, 0, stream>>>(yhat, u2t, eb, kmm, tbl, lik);
    else
        k_mc_direct<<<NB, 256, 0, stream>>>(yhat, u2t, eb, lik);
}